// Round 1
// baseline (542.633 us; speedup 1.0000x reference)
//
#include <hip/hip_runtime.h>
#include <cstdint>
#include <cstddef>

// Match XLA: no FMA contraction anywhere in this TU (mul and add rounded separately).
#pragma clang fp contract(off)

#define N_PIX    524288     // 8*256*256 output pixels
#define CSPLANES 112        // 4*28 reduced planes
#define PLANE    65536      // 256*256
#define DCH      48         // max PRNG-loop depth (P(exceed) ~ 1e-30)
#define NBLK     512        // 512 blk x 1024 thr = 524288 thr: 2 blk/CU, 32 waves/CU (100%)

// ---------------- Threefry-2x32 (exact JAX semantics) ----------------
struct TF2 { uint32_t a, b; };

__host__ __device__ constexpr uint32_t rotl32(uint32_t x, int d) {
  return (x << d) | (x >> (32 - d));
}

__host__ __device__ constexpr TF2 threefry(uint32_t k0, uint32_t k1,
                                           uint32_t c0, uint32_t c1) {
  uint32_t ks2 = k0 ^ k1 ^ 0x1BD11BDAu;
  uint32_t x0 = c0 + k0;
  uint32_t x1 = c1 + k1;
  const int R0[4] = {13, 15, 26, 6};
  const int R1[4] = {17, 29, 16, 24};
  for (int i = 0; i < 4; ++i) { x0 += x1; x1 = rotl32(x1, R0[i]); x1 ^= x0; }
  x0 += k1;  x1 += ks2 + 1u;
  for (int i = 0; i < 4; ++i) { x0 += x1; x1 = rotl32(x1, R1[i]); x1 ^= x0; }
  x0 += ks2; x1 += k0 + 2u;
  for (int i = 0; i < 4; ++i) { x0 += x1; x1 = rotl32(x1, R0[i]); x1 ^= x0; }
  x0 += k0;  x1 += k1 + 3u;
  for (int i = 0; i < 4; ++i) { x0 += x1; x1 = rotl32(x1, R1[i]); x1 ^= x0; }
  x0 += k1;  x1 += ks2 + 4u;
  for (int i = 0; i < 4; ++i) { x0 += x1; x1 = rotl32(x1, R0[i]); x1 ^= x0; }
  x0 += ks2; x1 += k0 + 5u;
  return TF2{x0, x1};
}

// Key chains for the samplers, computed at COMPILE TIME (key = jax.random.key(1)).
// Convention: jax_threefry_partitionable = True (default since jax 0.4.36):
//   split(key, n)[i] = threefry(key, (0, i));  random_bits[j] = x0^x1 of threefry(key, (0, j))
struct Chains {
  uint32_t kg0, kg1;                                   // normal key
  uint32_t rj0a[DCH], rj0b[DCH], rj1a[DCH], rj1b[DCH]; // rejection split-3 chain from kp
  uint32_t kda[DCH], kdb[DCH];                         // knuth split-2 chain from kd
  uint32_t kpa[DCH], kpb[DCH];                         // knuth split-2 chain from kp (lam<10 fallback)
};

__host__ __device__ constexpr Chains make_chains() {
  Chains c{};
  TF2 kp = threefry(0u, 1u, 0u, 0u);   // split(key(1), 3) rows 0..2
  TF2 kd = threefry(0u, 1u, 0u, 1u);
  TF2 kg = threefry(0u, 1u, 0u, 2u);
  c.kg0 = kg.a; c.kg1 = kg.b;
  {
    uint32_t a = kp.a, b = kp.b;
    for (int i = 0; i < DCH; ++i) {
      TF2 nk = threefry(a, b, 0u, 0u);
      TF2 s0 = threefry(a, b, 0u, 1u);
      TF2 s1 = threefry(a, b, 0u, 2u);
      c.rj0a[i] = s0.a; c.rj0b[i] = s0.b;
      c.rj1a[i] = s1.a; c.rj1b[i] = s1.b;
      a = nk.a; b = nk.b;
    }
  }
  {
    uint32_t a = kd.a, b = kd.b;
    for (int i = 0; i < DCH; ++i) {
      TF2 nk = threefry(a, b, 0u, 0u);
      TF2 sk = threefry(a, b, 0u, 1u);
      c.kda[i] = sk.a; c.kdb[i] = sk.b;
      a = nk.a; b = nk.b;
    }
  }
  {
    uint32_t a = kp.a, b = kp.b;
    for (int i = 0; i < DCH; ++i) {
      TF2 nk = threefry(a, b, 0u, 0u);
      TF2 sk = threefry(a, b, 0u, 1u);
      c.kpa[i] = sk.a; c.kpb[i] = sk.b;
      a = nk.a; b = nk.b;
    }
  }
  return c;
}

__constant__ Chains G = make_chains();

// uniform [0,1) for flat element j under a given key (partitionable bit path)
__device__ inline float u01(uint32_t k0, uint32_t k1, uint32_t j) {
  TF2 r = threefry(k0, k1, 0u, j);
  uint32_t bits = r.a ^ r.b;
  return __uint_as_float((bits >> 9) | 0x3F800000u) - 1.0f;
}

// ---------------- XLA-exact special functions (f32, Lanczos / Giles) ----------------
__device__ inline float xla_lgamma(float x_in) {
  // no-reflection path only (argument k+1 >= 1 whenever the result matters)
  float z = x_in - 1.0f;
  float x = 1.0f;  // f32(kBaseLanczosCoeff)
  x = x + 676.520368121885098567009190444019f    / ((z + 0.0f) + 1.0f);
  x = x + (-1259.13921672240287047156078755283f) / ((z + 1.0f) + 1.0f);
  x = x + 771.3234287776530788486528258894f      / ((z + 2.0f) + 1.0f);
  x = x + (-176.61502916214059906584551354f)     / ((z + 3.0f) + 1.0f);
  x = x + 12.507343278686904814458936853f        / ((z + 4.0f) + 1.0f);
  x = x + (-0.13857109526572011689554707f)       / ((z + 5.0f) + 1.0f);
  x = x + 9.984369578019570859563e-6f            / ((z + 6.0f) + 1.0f);
  x = x + 1.50563273514931155834e-7f             / ((z + 7.0f) + 1.0f);
  float t = 7.5f + z;
  float log_t = 2.0149030205422647f + log1pf(z / 7.5f);
  return 0.91893853320467274178f + ((z + 0.5f) - t / log_t) * log_t + logf(x);
}

__device__ inline float xla_erfinv(float xx) {  // Giles 2012, as in XLA ErfInv32
  float w = -log1pf(-(xx * xx));
  float p;
  if (w < 5.0f) {
    float ww = w - 2.5f;
    p = 2.81022636e-08f;
    p = 3.43273939e-07f + p * ww;
    p = -3.5233877e-06f + p * ww;
    p = -4.39150654e-06f + p * ww;
    p = 0.00021858087f + p * ww;
    p = -0.00125372503f + p * ww;
    p = -0.00417768164f + p * ww;
    p = 0.246640727f + p * ww;
    p = 1.50140941f + p * ww;
  } else {
    float ww = sqrtf(w) - 3.0f;
    p = -0.000200214257f;
    p = 0.000100950558f + p * ww;
    p = 0.00134934322f + p * ww;
    p = -0.00367342844f + p * ww;
    p = 0.00573950773f + p * ww;
    p = -0.0076224613f + p * ww;
    p = 0.00943887047f + p * ww;
    p = 1.00167406f + p * ww;
    p = 2.83297682f + p * ww;
  }
  return p * xx;
}

__device__ inline float xla_normal(uint32_t j) {   // jax.random.normal(kg)[j]
  const float lo = -0.999999940395355224609375f;   // nextafter(-1, 0) in f32
  float f = u01(G.kg0, G.kg1, j);
  float u = f * (1.0f - lo) + lo;                  // (1-lo) folds to 2.0f, XLA-identical
  u = fmaxf(lo, u);
  return 1.41421356237309504880f * xla_erfinv(u);  // f32(np.sqrt(2))
}

// ---------------- JAX poisson samplers ----------------
__device__ inline int knuth_sample(const uint32_t* ka, const uint32_t* kb,
                                   uint32_t j, float lam) {
  const float neg = -lam;
  int k = 0;
  float lp = 0.0f;
  #pragma unroll 1
  for (int i = 0; i < DCH; ++i) {
    if (!(lp > neg)) break;
    ++k;
    float uu = u01(ka[i], kb[i], j);
    lp = lp + logf(uu);
  }
  return k - 1;
}

struct RejC { float lam, loglam, a, b, inva, vr; };

__device__ inline RejC make_rc(float lam) {
  RejC rc;
  rc.lam = lam;
  rc.loglam = logf(lam);
  rc.b = 0.931f + 2.53f * sqrtf(lam);
  rc.a = -0.059f + 0.02483f * rc.b;
  rc.inva = 1.1239f + 1.1328f / (rc.b - 3.4f);
  rc.vr = 0.9277f - 3.6224f / (rc.b - 2.0f);
  return rc;
}

// One body of jax's _poisson_rejection while-loop (iteration index i, 0-based)
__device__ inline bool rej_step(const RejC& rc, uint32_t j, int i, float* kout) {
  float u = u01(G.rj0a[i], G.rj0b[i], j) - 0.5f;
  float v = u01(G.rj1a[i], G.rj1b[i], j);
  float us = 0.5f - fabsf(u);
  float k = floorf(((2.0f * rc.a / us + rc.b) * u + rc.lam) + 0.43f);
  *kout = k;
  bool accept1 = (us >= 0.07f) && (v <= rc.vr);
  if (accept1) return true;
  bool reject = (k < 0.0f) || ((us < 0.013f) && (v > us));
  if (reject) return false;
  float s = logf(v * rc.inva / (rc.a / (us * us) + rc.b));
  float t = (-rc.lam + k * rc.loglam) - xla_lgamma(k + 1.0f);
  return s <= t;
}

__device__ inline unsigned first_accept(const RejC& rc, uint32_t j) {
  unsigned F = DCH;
  #pragma unroll 1
  for (int i = 0; i < DCH; ++i) {   // first-accept iteration (jax's global T input)
    float kc;
    if (rej_step(rc, j, i, &kc)) { F = (unsigned)(i + 1); break; }
  }
  return F;
}

__device__ inline float resolve_pix(const RejC& rc, float peak, uint32_t j, int T) {
  if (peak >= 10.0f) {
    float kk = -1.0f;
    #pragma unroll 1
    for (int i = T - 1; i >= 0; --i) {   // downward scan: first hit = last accept <= T
      float kc;
      if (rej_step(rc, j, i, &kc)) { kk = kc; break; }
    }
    return (float)(int)kk;
  } else if (peak <= 0.0f) {
    return 0.0f;
  } else {
    return (float)knuth_sample(G.kpa, G.kpb, j, peak);
  }
}

// ---------------- Fused kernel: reduce -> noise -> grid barrier (T) -> resolve ----------------
// Grid = 512 blocks x 1024 threads, ONE pixel per thread (full 524288-thread chip
// residency: 2 blocks/CU x 16 waves = 32 waves/CU). __launch_bounds__(1024, 8)
// caps VGPRs at 64 so 2 blocks/CU always fit -> spin barrier deadlock-free.
// Reduce phase: 7 chunks of 16 planes with statically-indexed register arrays ->
// 32 dword loads in flight per wave (8KB/wave, 256KB/CU) to cover HBM latency.
// Per-pixel arithmetic order identical to previous version -> bit-identical output.
// sync[0] = global T (atomicMax), sync[1] = arrival count.
__global__ __launch_bounds__(1024, 8) void fused_kernel(const float* __restrict__ spec,
                                                        const float* __restrict__ filt,
                                                        float* __restrict__ out,
                                                        unsigned* __restrict__ sync) {
  const int tid = threadIdx.x;
  const int pixbase = blockIdx.x << 10;          // 1024 pixels per block
  const int b_img = pixbase >> 16;               // 64 blocks per image: never straddle a batch
  const int hw = (pixbase & 65535) + tid;
  const size_t base = (size_t)b_img * ((size_t)CSPLANES * PLANE) + (size_t)hw;
  const float* sp = spec + base;
  const float* fp = filt + base;

  // serial-112 accumulation order == previous rounds (absmax 0.43)
  float a = 0.f;
  #pragma unroll 1
  for (int c = 0; c < CSPLANES; c += 16) {
    float ss[16], ff[16];
    #pragma unroll
    for (int i = 0; i < 16; ++i) ss[i] = sp[(size_t)(c + i) * PLANE];
    #pragma unroll
    for (int i = 0; i < 16; ++i) ff[i] = fp[(size_t)(c + i) * PLANE];
    #pragma unroll
    for (int i = 0; i < 16; ++i) a = a + ss[i] * ff[i];
  }

  const uint32_t j = (uint32_t)(pixbase + tid);
  const float pk = a + 1e-10f;
  const float d = (float)knuth_sample(G.kda, G.kdb, j, 0.5f);
  const float g = xla_normal(j) * 0.5f;
  const RejC rc = make_rc(pk);
  unsigned F = first_accept(rc, j);

  // wave max -> block max -> device max + arrival barrier
  for (int off = 32; off; off >>= 1) {
    unsigned o = (unsigned)__shfl_down((int)F, off, 64);
    F = F > o ? F : o;
  }
  __shared__ unsigned sred[16];
  __shared__ int sT;
  if ((tid & 63) == 0) sred[tid >> 6] = F;
  __syncthreads();
  if (tid == 0) {
    unsigned m = sred[0];
    #pragma unroll
    for (int i = 1; i < 16; ++i) m = m > sred[i] ? m : sred[i];
    __hip_atomic_fetch_max(&sync[0], m, __ATOMIC_RELAXED, __HIP_MEMORY_SCOPE_AGENT);
    __hip_atomic_fetch_add(&sync[1], 1u, __ATOMIC_ACQ_REL, __HIP_MEMORY_SCOPE_AGENT);
    while (__hip_atomic_load(&sync[1], __ATOMIC_ACQUIRE, __HIP_MEMORY_SCOPE_AGENT) < (unsigned)NBLK) {
      __builtin_amdgcn_s_sleep(8);
    }
    sT = (int)__hip_atomic_load(&sync[0], __ATOMIC_RELAXED, __HIP_MEMORY_SCOPE_AGENT);
  }
  __syncthreads();
  const int T = sT;

  const float pv = resolve_pix(rc, pk, j, T);
  const float n = ((pv + d) + g) * 10.0f / 255.0f;

  out[j]             = n;      // output 0: noisy
  out[N_PIX + j]     = pk;     // output 1: peak
  out[2 * N_PIX + j] = 0.5f;   // output 2: dark_t
  out[3 * N_PIX + j] = 0.25f;  // output 3: gauss_t^2
}

extern "C" void kernel_launch(void* const* d_in, const int* in_sizes, int n_in,
                              void* d_out, int out_size, void* d_ws, size_t ws_size,
                              hipStream_t stream) {
  (void)in_sizes; (void)n_in; (void)out_size; (void)ws_size;
  const float* spec = (const float*)d_in[0];
  const float* filt = (const float*)d_in[1];
  float* out = (float*)d_out;
  unsigned* sync = (unsigned*)d_ws;
  (void)hipMemsetAsync(d_ws, 0, 2 * sizeof(unsigned), stream);
  hipLaunchKernelGGL(fused_kernel, dim3(NBLK), dim3(1024), 0, stream,
                     spec, filt, out, sync);
}

// Round 2
// 502.592 us; speedup vs baseline: 1.0797x; 1.0797x over previous
//
#include <hip/hip_runtime.h>
#include <cstdint>
#include <cstddef>

// Match XLA: no FMA contraction anywhere in this TU (mul and add rounded separately).
#pragma clang fp contract(off)

#define N_PIX    524288     // 8*256*256 output pixels
#define CSPLANES 112        // 4*28 reduced planes
#define PLANE    65536      // 256*256
#define DCH      48         // max PRNG-loop depth (P(exceed) ~ 1e-30)

// ---------------- Threefry-2x32 (exact JAX semantics) ----------------
struct TF2 { uint32_t a, b; };

__host__ __device__ constexpr uint32_t rotl32(uint32_t x, int d) {
  return (x << d) | (x >> (32 - d));
}

__host__ __device__ constexpr TF2 threefry(uint32_t k0, uint32_t k1,
                                           uint32_t c0, uint32_t c1) {
  uint32_t ks2 = k0 ^ k1 ^ 0x1BD11BDAu;
  uint32_t x0 = c0 + k0;
  uint32_t x1 = c1 + k1;
  const int R0[4] = {13, 15, 26, 6};
  const int R1[4] = {17, 29, 16, 24};
  for (int i = 0; i < 4; ++i) { x0 += x1; x1 = rotl32(x1, R0[i]); x1 ^= x0; }
  x0 += k1;  x1 += ks2 + 1u;
  for (int i = 0; i < 4; ++i) { x0 += x1; x1 = rotl32(x1, R1[i]); x1 ^= x0; }
  x0 += ks2; x1 += k0 + 2u;
  for (int i = 0; i < 4; ++i) { x0 += x1; x1 = rotl32(x1, R0[i]); x1 ^= x0; }
  x0 += k0;  x1 += k1 + 3u;
  for (int i = 0; i < 4; ++i) { x0 += x1; x1 = rotl32(x1, R1[i]); x1 ^= x0; }
  x0 += k1;  x1 += ks2 + 4u;
  for (int i = 0; i < 4; ++i) { x0 += x1; x1 = rotl32(x1, R0[i]); x1 ^= x0; }
  x0 += ks2; x1 += k0 + 5u;
  return TF2{x0, x1};
}

// Key chains for the samplers, computed at COMPILE TIME (key = jax.random.key(1)).
// Convention: jax_threefry_partitionable = True (default since jax 0.4.36):
//   split(key, n)[i] = threefry(key, (0, i));  random_bits[j] = x0^x1 of threefry(key, (0, j))
struct Chains {
  uint32_t kg0, kg1;                                   // normal key
  uint32_t rj0a[DCH], rj0b[DCH], rj1a[DCH], rj1b[DCH]; // rejection split-3 chain from kp
  uint32_t kda[DCH], kdb[DCH];                         // knuth split-2 chain from kd
  uint32_t kpa[DCH], kpb[DCH];                         // knuth split-2 chain from kp (lam<10 fallback)
};

__host__ __device__ constexpr Chains make_chains() {
  Chains c{};
  TF2 kp = threefry(0u, 1u, 0u, 0u);   // split(key(1), 3) rows 0..2
  TF2 kd = threefry(0u, 1u, 0u, 1u);
  TF2 kg = threefry(0u, 1u, 0u, 2u);
  c.kg0 = kg.a; c.kg1 = kg.b;
  {
    uint32_t a = kp.a, b = kp.b;
    for (int i = 0; i < DCH; ++i) {
      TF2 nk = threefry(a, b, 0u, 0u);
      TF2 s0 = threefry(a, b, 0u, 1u);
      TF2 s1 = threefry(a, b, 0u, 2u);
      c.rj0a[i] = s0.a; c.rj0b[i] = s0.b;
      c.rj1a[i] = s1.a; c.rj1b[i] = s1.b;
      a = nk.a; b = nk.b;
    }
  }
  {
    uint32_t a = kd.a, b = kd.b;
    for (int i = 0; i < DCH; ++i) {
      TF2 nk = threefry(a, b, 0u, 0u);
      TF2 sk = threefry(a, b, 0u, 1u);
      c.kda[i] = sk.a; c.kdb[i] = sk.b;
      a = nk.a; b = nk.b;
    }
  }
  {
    uint32_t a = kp.a, b = kp.b;
    for (int i = 0; i < DCH; ++i) {
      TF2 nk = threefry(a, b, 0u, 0u);
      TF2 sk = threefry(a, b, 0u, 1u);
      c.kpa[i] = sk.a; c.kpb[i] = sk.b;
      a = nk.a; b = nk.b;
    }
  }
  return c;
}

__constant__ Chains G = make_chains();

// uniform [0,1) for flat element j under a given key (partitionable bit path)
__device__ inline float u01(uint32_t k0, uint32_t k1, uint32_t j) {
  TF2 r = threefry(k0, k1, 0u, j);
  uint32_t bits = r.a ^ r.b;
  return __uint_as_float((bits >> 9) | 0x3F800000u) - 1.0f;
}

// ---------------- XLA-exact special functions (f32, Lanczos / Giles) ----------------
__device__ inline float xla_lgamma(float x_in) {
  // no-reflection path only (argument k+1 >= 1 whenever the result matters)
  float z = x_in - 1.0f;
  float x = 1.0f;  // f32(kBaseLanczosCoeff)
  x = x + 676.520368121885098567009190444019f    / ((z + 0.0f) + 1.0f);
  x = x + (-1259.13921672240287047156078755283f) / ((z + 1.0f) + 1.0f);
  x = x + 771.3234287776530788486528258894f      / ((z + 2.0f) + 1.0f);
  x = x + (-176.61502916214059906584551354f)     / ((z + 3.0f) + 1.0f);
  x = x + 12.507343278686904814458936853f        / ((z + 4.0f) + 1.0f);
  x = x + (-0.13857109526572011689554707f)       / ((z + 5.0f) + 1.0f);
  x = x + 9.984369578019570859563e-6f            / ((z + 6.0f) + 1.0f);
  x = x + 1.50563273514931155834e-7f             / ((z + 7.0f) + 1.0f);
  float t = 7.5f + z;
  float log_t = 2.0149030205422647f + log1pf(z / 7.5f);
  return 0.91893853320467274178f + ((z + 0.5f) - t / log_t) * log_t + logf(x);
}

__device__ inline float xla_erfinv(float xx) {  // Giles 2012, as in XLA ErfInv32
  float w = -log1pf(-(xx * xx));
  float p;
  if (w < 5.0f) {
    float ww = w - 2.5f;
    p = 2.81022636e-08f;
    p = 3.43273939e-07f + p * ww;
    p = -3.5233877e-06f + p * ww;
    p = -4.39150654e-06f + p * ww;
    p = 0.00021858087f + p * ww;
    p = -0.00125372503f + p * ww;
    p = -0.00417768164f + p * ww;
    p = 0.246640727f + p * ww;
    p = 1.50140941f + p * ww;
  } else {
    float ww = sqrtf(w) - 3.0f;
    p = -0.000200214257f;
    p = 0.000100950558f + p * ww;
    p = 0.00134934322f + p * ww;
    p = -0.00367342844f + p * ww;
    p = 0.00573950773f + p * ww;
    p = -0.0076224613f + p * ww;
    p = 0.00943887047f + p * ww;
    p = 1.00167406f + p * ww;
    p = 2.83297682f + p * ww;
  }
  return p * xx;
}

__device__ inline float xla_normal(uint32_t j) {   // jax.random.normal(kg)[j]
  const float lo = -0.999999940395355224609375f;   // nextafter(-1, 0) in f32
  float f = u01(G.kg0, G.kg1, j);
  float u = f * (1.0f - lo) + lo;                  // (1-lo) folds to 2.0f, XLA-identical
  u = fmaxf(lo, u);
  return 1.41421356237309504880f * xla_erfinv(u);  // f32(np.sqrt(2))
}

// ---------------- JAX poisson samplers ----------------
__device__ inline int knuth_sample(const uint32_t* ka, const uint32_t* kb,
                                   uint32_t j, float lam) {
  const float neg = -lam;
  int k = 0;
  float lp = 0.0f;
  #pragma unroll 1
  for (int i = 0; i < DCH; ++i) {
    if (!(lp > neg)) break;
    ++k;
    float uu = u01(ka[i], kb[i], j);
    lp = lp + logf(uu);
  }
  return k - 1;
}

struct RejC { float lam, loglam, a, b, inva, vr; };

__device__ inline RejC make_rc(float lam) {
  RejC rc;
  rc.lam = lam;
  rc.loglam = logf(lam);
  rc.b = 0.931f + 2.53f * sqrtf(lam);
  rc.a = -0.059f + 0.02483f * rc.b;
  rc.inva = 1.1239f + 1.1328f / (rc.b - 3.4f);
  rc.vr = 0.9277f - 3.6224f / (rc.b - 2.0f);
  return rc;
}

// One body of jax's _poisson_rejection while-loop (iteration index i, 0-based)
__device__ inline bool rej_step(const RejC& rc, uint32_t j, int i, float* kout) {
  float u = u01(G.rj0a[i], G.rj0b[i], j) - 0.5f;
  float v = u01(G.rj1a[i], G.rj1b[i], j);
  float us = 0.5f - fabsf(u);
  float k = floorf(((2.0f * rc.a / us + rc.b) * u + rc.lam) + 0.43f);
  *kout = k;
  bool accept1 = (us >= 0.07f) && (v <= rc.vr);
  if (accept1) return true;
  bool reject = (k < 0.0f) || ((us < 0.013f) && (v > us));
  if (reject) return false;
  float s = logf(v * rc.inva / (rc.a / (us * us) + rc.b));
  float t = (-rc.lam + k * rc.loglam) - xla_lgamma(k + 1.0f);
  return s <= t;
}

__device__ inline unsigned first_accept(const RejC& rc, uint32_t j) {
  unsigned F = DCH;
  #pragma unroll 1
  for (int i = 0; i < DCH; ++i) {   // first-accept iteration (jax's global T input)
    float kc;
    if (rej_step(rc, j, i, &kc)) { F = (unsigned)(i + 1); break; }
  }
  return F;
}

__device__ inline float resolve_pix(const RejC& rc, float peak, uint32_t j, int T) {
  if (peak >= 10.0f) {
    float kk = -1.0f;
    #pragma unroll 1
    for (int i = T - 1; i >= 0; --i) {   // downward scan: first hit = last accept <= T
      float kc;
      if (rej_step(rc, j, i, &kc)) { kk = kc; break; }
    }
    return (float)(int)kk;
  } else if (peak <= 0.0f) {
    return 0.0f;
  } else {
    return (float)knuth_sample(G.kpa, G.kpb, j, peak);
  }
}

// ================= Phase 1: streaming reduce (BW-optimized geometry) ==============
// 512 blocks x 256 threads, 4 px/thread via float4: per-chunk 16 float4 loads
// (16 KB/wave in flight) pinned by sched_group_barrier so the register allocator
// cannot re-serialize them (round-1 lesson: VGPR=24 proved it does by default).
// 8 waves/CU is plenty: Little's law needs ~9 KB/CU in flight for 6.3 TB/s; we
// carry ~128 KB/CU. Writes output 1 (peak) -- needed anyway, so phase split is free.
__global__ __launch_bounds__(256) void reduce_kernel(const float* __restrict__ spec,
                                                     const float* __restrict__ filt,
                                                     float* __restrict__ out) {
  const int tid = threadIdx.x;
  const int pixbase = blockIdx.x << 10;          // 1024 px per block; 64 blocks/image
  const int b_img = pixbase >> 16;               // blocks never straddle a batch
  const int hw = (pixbase & 65535) + (tid << 2);
  const size_t base = (size_t)b_img * ((size_t)CSPLANES * PLANE) + (size_t)hw;
  const float* sp = spec + base;
  const float* fp = filt + base;

  // serial-112 per-pixel accumulation order == previous rounds (absmax 0.43)
  float4 acc = make_float4(0.f, 0.f, 0.f, 0.f);
  #pragma unroll 1
  for (int c = 0; c < CSPLANES; c += 8) {
    float4 ss[8], ff[8];
    #pragma unroll
    for (int i = 0; i < 8; ++i) ss[i] = *reinterpret_cast<const float4*>(sp + (size_t)(c + i) * PLANE);
    #pragma unroll
    for (int i = 0; i < 8; ++i) ff[i] = *reinterpret_cast<const float4*>(fp + (size_t)(c + i) * PLANE);
    __builtin_amdgcn_sched_group_barrier(0x020, 16, 0);   // 16 VMEM reads first...
    #pragma unroll
    for (int i = 0; i < 8; ++i) {
      acc.x = acc.x + ss[i].x * ff[i].x;
      acc.y = acc.y + ss[i].y * ff[i].y;
      acc.z = acc.z + ss[i].z * ff[i].z;
      acc.w = acc.w + ss[i].w * ff[i].w;
    }
    __builtin_amdgcn_sched_group_barrier(0x002, 64, 0);   // ...then the 64 VALU
  }

  const int j = pixbase + (tid << 2);
  float4 pk = make_float4(acc.x + 1e-10f, acc.y + 1e-10f,
                          acc.z + 1e-10f, acc.w + 1e-10f);
  *reinterpret_cast<float4*>(out + N_PIX + j) = pk;      // output 1: peak
}

// ================= Phase 2: global T via first-accept (occupancy-optimized) ========
// 2048 blocks x 256 threads, 1 px/thread. Reads peak (2 MB), no co-residency
// requirement, no spin barrier -- stream ordering is the barrier.
__global__ __launch_bounds__(256) void fmax_kernel(const float* __restrict__ out,
                                                   unsigned* __restrict__ sync) {
  const int j = (blockIdx.x << 8) + threadIdx.x;
  const float pk = out[N_PIX + j];
  const RejC rc = make_rc(pk);
  unsigned F = first_accept(rc, (uint32_t)j);

  for (int off = 32; off; off >>= 1) {
    unsigned o = (unsigned)__shfl_down((int)F, off, 64);
    F = F > o ? F : o;
  }
  __shared__ unsigned sred[4];
  if ((threadIdx.x & 63) == 0) sred[threadIdx.x >> 6] = F;
  __syncthreads();
  if (threadIdx.x == 0) {
    unsigned m = sred[0];
    #pragma unroll
    for (int i = 1; i < 4; ++i) m = m > sred[i] ? m : sred[i];
    __hip_atomic_fetch_max(&sync[0], m, __ATOMIC_RELAXED, __HIP_MEMORY_SCOPE_AGENT);
  }
}

// ================= Phase 3: noise synthesis + resolve (VALU-bound, high occ) =======
__global__ __launch_bounds__(256) void resolve_kernel(float* __restrict__ out,
                                                      const unsigned* __restrict__ sync) {
  const int j = (blockIdx.x << 8) + threadIdx.x;
  const int T = (int)__hip_atomic_load(&sync[0], __ATOMIC_RELAXED, __HIP_MEMORY_SCOPE_AGENT);
  const float pk = out[N_PIX + j];

  const float d = (float)knuth_sample(G.kda, G.kdb, (uint32_t)j, 0.5f);
  const float g = xla_normal((uint32_t)j) * 0.5f;
  const RejC rc = make_rc(pk);
  const float pv = resolve_pix(rc, pk, (uint32_t)j, T);
  const float n = ((pv + d) + g) * 10.0f / 255.0f;

  out[j]             = n;      // output 0: noisy
  out[2 * N_PIX + j] = 0.5f;   // output 2: dark_t
  out[3 * N_PIX + j] = 0.25f;  // output 3: gauss_t^2
}

extern "C" void kernel_launch(void* const* d_in, const int* in_sizes, int n_in,
                              void* d_out, int out_size, void* d_ws, size_t ws_size,
                              hipStream_t stream) {
  (void)in_sizes; (void)n_in; (void)out_size; (void)ws_size;
  const float* spec = (const float*)d_in[0];
  const float* filt = (const float*)d_in[1];
  float* out = (float*)d_out;
  unsigned* sync = (unsigned*)d_ws;
  (void)hipMemsetAsync(d_ws, 0, 2 * sizeof(unsigned), stream);
  hipLaunchKernelGGL(reduce_kernel, dim3(512), dim3(256), 0, stream, spec, filt, out);
  hipLaunchKernelGGL(fmax_kernel, dim3(2048), dim3(256), 0, stream, out, sync);
  hipLaunchKernelGGL(resolve_kernel, dim3(2048), dim3(256), 0, stream, out, sync);
}

// Round 5
// 494.299 us; speedup vs baseline: 1.0978x; 1.0168x over previous
//
#include <hip/hip_runtime.h>
#include <cstdint>
#include <cstddef>

// Match XLA: no FMA contraction anywhere in this TU (mul and add rounded separately).
#pragma clang fp contract(off)

#define N_PIX    524288     // 8*256*256 output pixels
#define CSPLANES 112        // 4*28 reduced planes
#define PLANE    65536      // 256*256
#define DCH      48         // max PRNG-loop depth (P(exceed) ~ 1e-30)

// ---------------- Threefry-2x32 (exact JAX semantics) ----------------
struct TF2 { uint32_t a, b; };

__host__ __device__ constexpr uint32_t rotl32(uint32_t x, int d) {
  return (x << d) | (x >> (32 - d));
}

__host__ __device__ constexpr TF2 threefry(uint32_t k0, uint32_t k1,
                                           uint32_t c0, uint32_t c1) {
  uint32_t ks2 = k0 ^ k1 ^ 0x1BD11BDAu;
  uint32_t x0 = c0 + k0;
  uint32_t x1 = c1 + k1;
  const int R0[4] = {13, 15, 26, 6};
  const int R1[4] = {17, 29, 16, 24};
  for (int i = 0; i < 4; ++i) { x0 += x1; x1 = rotl32(x1, R0[i]); x1 ^= x0; }
  x0 += k1;  x1 += ks2 + 1u;
  for (int i = 0; i < 4; ++i) { x0 += x1; x1 = rotl32(x1, R1[i]); x1 ^= x0; }
  x0 += ks2; x1 += k0 + 2u;
  for (int i = 0; i < 4; ++i) { x0 += x1; x1 = rotl32(x1, R0[i]); x1 ^= x0; }
  x0 += k0;  x1 += k1 + 3u;
  for (int i = 0; i < 4; ++i) { x0 += x1; x1 = rotl32(x1, R1[i]); x1 ^= x0; }
  x0 += k1;  x1 += ks2 + 4u;
  for (int i = 0; i < 4; ++i) { x0 += x1; x1 = rotl32(x1, R0[i]); x1 ^= x0; }
  x0 += ks2; x1 += k0 + 5u;
  return TF2{x0, x1};
}

// Key chains for the samplers, computed at COMPILE TIME (key = jax.random.key(1)).
// Convention: jax_threefry_partitionable = True (default since jax 0.4.36):
//   split(key, n)[i] = threefry(key, (0, i));  random_bits[j] = x0^x1 of threefry(key, (0, j))
struct Chains {
  uint32_t kg0, kg1;                                   // normal key
  uint32_t rj0a[DCH], rj0b[DCH], rj1a[DCH], rj1b[DCH]; // rejection split-3 chain from kp
  uint32_t kda[DCH], kdb[DCH];                         // knuth split-2 chain from kd
  uint32_t kpa[DCH], kpb[DCH];                         // knuth split-2 chain from kp (lam<10 fallback)
};

__host__ __device__ constexpr Chains make_chains() {
  Chains c{};
  TF2 kp = threefry(0u, 1u, 0u, 0u);   // split(key(1), 3) rows 0..2
  TF2 kd = threefry(0u, 1u, 0u, 1u);
  TF2 kg = threefry(0u, 1u, 0u, 2u);
  c.kg0 = kg.a; c.kg1 = kg.b;
  {
    uint32_t a = kp.a, b = kp.b;
    for (int i = 0; i < DCH; ++i) {
      TF2 nk = threefry(a, b, 0u, 0u);
      TF2 s0 = threefry(a, b, 0u, 1u);
      TF2 s1 = threefry(a, b, 0u, 2u);
      c.rj0a[i] = s0.a; c.rj0b[i] = s0.b;
      c.rj1a[i] = s1.a; c.rj1b[i] = s1.b;
      a = nk.a; b = nk.b;
    }
  }
  {
    uint32_t a = kd.a, b = kd.b;
    for (int i = 0; i < DCH; ++i) {
      TF2 nk = threefry(a, b, 0u, 0u);
      TF2 sk = threefry(a, b, 0u, 1u);
      c.kda[i] = sk.a; c.kdb[i] = sk.b;
      a = nk.a; b = nk.b;
    }
  }
  {
    uint32_t a = kp.a, b = kp.b;
    for (int i = 0; i < DCH; ++i) {
      TF2 nk = threefry(a, b, 0u, 0u);
      TF2 sk = threefry(a, b, 0u, 1u);
      c.kpa[i] = sk.a; c.kpb[i] = sk.b;
      a = nk.a; b = nk.b;
    }
  }
  return c;
}

__constant__ Chains G = make_chains();

// uniform [0,1) for flat element j under a given key (partitionable bit path)
__device__ inline float u01(uint32_t k0, uint32_t k1, uint32_t j) {
  TF2 r = threefry(k0, k1, 0u, j);
  uint32_t bits = r.a ^ r.b;
  return __uint_as_float((bits >> 9) | 0x3F800000u) - 1.0f;
}

// ---------------- XLA-exact special functions (f32, Lanczos / Giles) ----------------
__device__ inline float xla_lgamma(float x_in) {
  // no-reflection path only (argument k+1 >= 1 whenever the result matters)
  float z = x_in - 1.0f;
  float x = 1.0f;  // f32(kBaseLanczosCoeff)
  x = x + 676.520368121885098567009190444019f    / ((z + 0.0f) + 1.0f);
  x = x + (-1259.13921672240287047156078755283f) / ((z + 1.0f) + 1.0f);
  x = x + 771.3234287776530788486528258894f      / ((z + 2.0f) + 1.0f);
  x = x + (-176.61502916214059906584551354f)     / ((z + 3.0f) + 1.0f);
  x = x + 12.507343278686904814458936853f        / ((z + 4.0f) + 1.0f);
  x = x + (-0.13857109526572011689554707f)       / ((z + 5.0f) + 1.0f);
  x = x + 9.984369578019570859563e-6f            / ((z + 6.0f) + 1.0f);
  x = x + 1.50563273514931155834e-7f             / ((z + 7.0f) + 1.0f);
  float t = 7.5f + z;
  float log_t = 2.0149030205422647f + log1pf(z / 7.5f);
  return 0.91893853320467274178f + ((z + 0.5f) - t / log_t) * log_t + logf(x);
}

__device__ inline float xla_erfinv(float xx) {  // Giles 2012, as in XLA ErfInv32
  float w = -log1pf(-(xx * xx));
  float p;
  if (w < 5.0f) {
    float ww = w - 2.5f;
    p = 2.81022636e-08f;
    p = 3.43273939e-07f + p * ww;
    p = -3.5233877e-06f + p * ww;
    p = -4.39150654e-06f + p * ww;
    p = 0.00021858087f + p * ww;
    p = -0.00125372503f + p * ww;
    p = -0.00417768164f + p * ww;
    p = 0.246640727f + p * ww;
    p = 1.50140941f + p * ww;
  } else {
    float ww = sqrtf(w) - 3.0f;
    p = -0.000200214257f;
    p = 0.000100950558f + p * ww;
    p = 0.00134934322f + p * ww;
    p = -0.00367342844f + p * ww;
    p = 0.00573950773f + p * ww;
    p = -0.0076224613f + p * ww;
    p = 0.00943887047f + p * ww;
    p = 1.00167406f + p * ww;
    p = 2.83297682f + p * ww;
  }
  return p * xx;
}

__device__ inline float xla_normal(uint32_t j) {   // jax.random.normal(kg)[j]
  const float lo = -0.999999940395355224609375f;   // nextafter(-1, 0) in f32
  float f = u01(G.kg0, G.kg1, j);
  float u = f * (1.0f - lo) + lo;                  // (1-lo) folds to 2.0f, XLA-identical
  u = fmaxf(lo, u);
  return 1.41421356237309504880f * xla_erfinv(u);  // f32(np.sqrt(2))
}

// ---------------- JAX poisson samplers ----------------
__device__ inline int knuth_sample(const uint32_t* ka, const uint32_t* kb,
                                   uint32_t j, float lam) {
  const float neg = -lam;
  int k = 0;
  float lp = 0.0f;
  #pragma unroll 1
  for (int i = 0; i < DCH; ++i) {
    if (!(lp > neg)) break;
    ++k;
    float uu = u01(ka[i], kb[i], j);
    lp = lp + logf(uu);
  }
  return k - 1;
}

struct RejC { float lam, loglam, a, b, inva, vr; };

__device__ inline RejC make_rc(float lam) {
  RejC rc;
  rc.lam = lam;
  rc.loglam = logf(lam);
  rc.b = 0.931f + 2.53f * sqrtf(lam);
  rc.a = -0.059f + 0.02483f * rc.b;
  rc.inva = 1.1239f + 1.1328f / (rc.b - 3.4f);
  rc.vr = 0.9277f - 3.6224f / (rc.b - 2.0f);
  return rc;
}

// One body of jax's _poisson_rejection while-loop (iteration index i, 0-based)
__device__ inline bool rej_step(const RejC& rc, uint32_t j, int i, float* kout) {
  float u = u01(G.rj0a[i], G.rj0b[i], j) - 0.5f;
  float v = u01(G.rj1a[i], G.rj1b[i], j);
  float us = 0.5f - fabsf(u);
  float k = floorf(((2.0f * rc.a / us + rc.b) * u + rc.lam) + 0.43f);
  *kout = k;
  bool accept1 = (us >= 0.07f) && (v <= rc.vr);
  if (accept1) return true;
  bool reject = (k < 0.0f) || ((us < 0.013f) && (v > us));
  if (reject) return false;
  float s = logf(v * rc.inva / (rc.a / (us * us) + rc.b));
  float t = (-rc.lam + k * rc.loglam) - xla_lgamma(k + 1.0f);
  return s <= t;
}

__device__ inline unsigned first_accept(const RejC& rc, uint32_t j) {
  unsigned F = DCH;
  #pragma unroll 1
  for (int i = 0; i < DCH; ++i) {   // first-accept iteration (jax's global T input)
    float kc;
    if (rej_step(rc, j, i, &kc)) { F = (unsigned)(i + 1); break; }
  }
  return F;
}

__device__ inline float resolve_pix(const RejC& rc, float peak, uint32_t j, int T) {
  if (peak >= 10.0f) {
    float kk = -1.0f;
    #pragma unroll 1
    for (int i = T - 1; i >= 0; --i) {   // downward scan: first hit = last accept <= T
      float kc;
      if (rej_step(rc, j, i, &kc)) { kk = kc; break; }
    }
    return (float)(int)kk;
  } else if (peak <= 0.0f) {
    return 0.0f;
  } else {
    return (float)knuth_sample(G.kpa, G.kpb, j, peak);
  }
}

// ================= Phase 1: streaming reduce via global_load_lds DMA ===============
// Rounds 3-4 post-mortem: asm loads into compiler-allocated VGPRs are UNSOUND --
// regalloc inserts v_mov copies of the "defined" registers before the hand-placed
// waitcnt (no compiler wait: it doesn't know the asm is a load) -> garbage.
// global_load_lds has NO VGPR destination (DMA to LDS), so that hazard cannot
// exist; the consume side is ds_read whose result registers the compiler tracks
// and fences itself (lgkmcnt). We hand-manage only the staging vmcnt.
// Geometry: 512 blk x 256 thr (4 waves), 4 px/thread. Each wave owns a private
// 16 KB LDS slice = 2 buffers x (4 planes x {spec,filt}) x 1 KB; no cross-wave
// sharing -> no barriers in the stream loop. 8 gl_lds (8 KB) in flight per wait
// window per wave; 8 waves/CU -> ~55 B/cyc/CU issueable vs 10.3 needed for the
// HBM share, so BW-saturating even if the compiler adds conservative drains.
// Lanes are 16B-contiguous -> matches gl_lds's linear LDS write (base+lane*16).
typedef float f32x4 __attribute__((ext_vector_type(4)));

__device__ __forceinline__ void glds16(const float* g, float* l) {
  __builtin_amdgcn_global_load_lds(
      (const __attribute__((address_space(1))) void*)g,
      (__attribute__((address_space(3))) void*)l,
      16 /*bytes, literal*/, 0 /*offset*/, 0 /*aux*/);
}

// counted staging wait; rule #18: sched_barrier(0) right after any asm waitcnt
#define WAITC(N)                                                          \
  asm volatile("s_waitcnt vmcnt(" #N ")" ::: "memory");                   \
  __builtin_amdgcn_sched_barrier(0);

// WAR fence: ds_reads of a buffer must complete before DMA re-stages into it
#define LGKM0                                                             \
  asm volatile("s_waitcnt lgkmcnt(0)" ::: "memory");                      \
  __builtin_amdgcn_sched_barrier(0);

#define STAGE(B, CBASE)                                                   \
  {                                                                       \
    _Pragma("unroll")                                                     \
    for (int s = 0; s < 4; ++s)                                           \
      glds16(sp + (size_t)((CBASE) + s) * PLANE,                          \
             wbase + (B) * 2048 + s * 256);                               \
    _Pragma("unroll")                                                     \
    for (int s = 0; s < 4; ++s)                                           \
      glds16(fp + (size_t)((CBASE) + s) * PLANE,                          \
             wbase + (B) * 2048 + (4 + s) * 256);                         \
  }

#define CONSUME(B)                                                        \
  {                                                                       \
    _Pragma("unroll")                                                     \
    for (int s = 0; s < 4; ++s) {                                         \
      f32x4 sv = *reinterpret_cast<f32x4*>(wbase + (B) * 2048 + s * 256 + (lane << 2));       \
      f32x4 fv = *reinterpret_cast<f32x4*>(wbase + (B) * 2048 + (4 + s) * 256 + (lane << 2)); \
      ax = ax + sv[0] * fv[0];                                            \
      ay = ay + sv[1] * fv[1];                                            \
      az = az + sv[2] * fv[2];                                            \
      aw = aw + sv[3] * fv[3];                                            \
    }                                                                     \
  }

__global__ __launch_bounds__(256, 2) void reduce_kernel(const float* __restrict__ spec,
                                                        const float* __restrict__ filt,
                                                        float* __restrict__ out,
                                                        unsigned* __restrict__ sync) {
  const int tid = threadIdx.x;
  const int wid = tid >> 6;
  const int lane = tid & 63;
  const int pixbase = blockIdx.x << 10;          // 1024 px per block; 64 blocks/image
  const int b_img = pixbase >> 16;               // blocks never straddle a batch
  const int hw = (pixbase & 65535) + (tid << 2);
  const size_t base = (size_t)b_img * ((size_t)CSPLANES * PLANE) + (size_t)hw;
  const float* sp = spec + base;
  const float* fp = filt + base;

  __shared__ float lds[16384];                   // 64 KB: 4 waves x 2 buf x 8 KB
  float* wbase = &lds[wid << 12];                // private 16 KB wave slice

  float ax = 0.f, ay = 0.f, az = 0.f, aw = 0.f;

  // 28 chunks of 4 planes, ascending plane order == previous rounds (absmax 0.43)
  STAGE(0, 0);
  STAGE(1, 4);
  #pragma unroll 1
  for (int c = 0; c < 104; c += 8) {
    WAITC(8);                  // buffer 0 (planes c..c+3) landed in LDS
    CONSUME(0);
    LGKM0;                     // reads done -> safe to DMA-overwrite buffer 0
    STAGE(0, c + 8);
    WAITC(8);                  // buffer 1 (planes c+4..c+7) landed
    CONSUME(1);
    LGKM0;
    STAGE(1, c + 12);
  }
  WAITC(8);
  CONSUME(0);                  // planes 104..107
  WAITC(0);
  CONSUME(1);                  // planes 108..111

  const int j = pixbase + (tid << 2);
  const float pk0 = ax + 1e-10f;
  const float pk1 = ay + 1e-10f;
  const float pk2 = az + 1e-10f;
  const float pk3 = aw + 1e-10f;
  f32x4 pkv; pkv[0] = pk0; pkv[1] = pk1; pkv[2] = pk2; pkv[3] = pk3;
  *reinterpret_cast<f32x4*>(out + N_PIX + j) = pkv;    // output 1: peak

  // folded global-T (round-0-proven logic): first_accept from register pk
  const uint32_t j0 = (uint32_t)j;
  const RejC rc0 = make_rc(pk0);
  const RejC rc1 = make_rc(pk1);
  const RejC rc2 = make_rc(pk2);
  const RejC rc3 = make_rc(pk3);
  unsigned F = first_accept(rc0, j0);
  { unsigned f = first_accept(rc1, j0 + 1u); if (f > F) F = f; }
  { unsigned f = first_accept(rc2, j0 + 2u); if (f > F) F = f; }
  { unsigned f = first_accept(rc3, j0 + 3u); if (f > F) F = f; }

  for (int off = 32; off; off >>= 1) {
    unsigned o = (unsigned)__shfl_down((int)F, off, 64);
    F = F > o ? F : o;
  }
  // reuse streaming LDS for the block reduction; barrier first so no wave is
  // still consuming its slice when another wave's lane 0 writes here
  unsigned* sred = reinterpret_cast<unsigned*>(lds);
  __syncthreads();
  if (lane == 0) sred[wid] = F;
  __syncthreads();
  if (tid == 0) {
    unsigned m = sred[0];
    #pragma unroll
    for (int i = 1; i < 4; ++i) m = m > sred[i] ? m : sred[i];
    __hip_atomic_fetch_max(&sync[0], m, __ATOMIC_RELAXED, __HIP_MEMORY_SCOPE_AGENT);
  }
}

// ================= Phase 2: noise synthesis + resolve (VALU-bound, high occ) =======
__global__ __launch_bounds__(256) void resolve_kernel(float* __restrict__ out,
                                                      const unsigned* __restrict__ sync) {
  const int j = (blockIdx.x << 8) + threadIdx.x;
  const int T = (int)__hip_atomic_load(&sync[0], __ATOMIC_RELAXED, __HIP_MEMORY_SCOPE_AGENT);
  const float pk = out[N_PIX + j];

  const float d = (float)knuth_sample(G.kda, G.kdb, (uint32_t)j, 0.5f);
  const float g = xla_normal((uint32_t)j) * 0.5f;
  const RejC rc = make_rc(pk);
  const float pv = resolve_pix(rc, pk, (uint32_t)j, T);
  const float n = ((pv + d) + g) * 10.0f / 255.0f;

  out[j]             = n;      // output 0: noisy
  out[2 * N_PIX + j] = 0.5f;   // output 2: dark_t
  out[3 * N_PIX + j] = 0.25f;  // output 3: gauss_t^2
}

extern "C" void kernel_launch(void* const* d_in, const int* in_sizes, int n_in,
                              void* d_out, int out_size, void* d_ws, size_t ws_size,
                              hipStream_t stream) {
  (void)in_sizes; (void)n_in; (void)out_size; (void)ws_size;
  const float* spec = (const float*)d_in[0];
  const float* filt = (const float*)d_in[1];
  float* out = (float*)d_out;
  unsigned* sync = (unsigned*)d_ws;
  (void)hipMemsetAsync(d_ws, 0, 2 * sizeof(unsigned), stream);
  hipLaunchKernelGGL(reduce_kernel, dim3(512), dim3(256), 0, stream, spec, filt, out, sync);
  hipLaunchKernelGGL(resolve_kernel, dim3(2048), dim3(256), 0, stream, out, sync);
}